// Round 8
// baseline (344.936 us; speedup 1.0000x reference)
//
#include <hip/hip_runtime.h>
#include <hip/hip_bf16.h>

#define C_DIM 256
#define C8 32
#define N_DIM 4096
#define B_DIM 8
#define SPLIT 2
#define KEYS_PER (N_DIM / SPLIT)   // 2048

using bf16x8 = __attribute__((ext_vector_type(8))) __bf16;
using bf16x4 = __attribute__((ext_vector_type(4))) __bf16;
using f32x4  = __attribute__((ext_vector_type(4))) float;
using f32x16 = __attribute__((ext_vector_type(16))) float;
using uint2v = __attribute__((ext_vector_type(2))) unsigned;

#define LOG2E 1.44269504088896f
#define SHIFT_L2 17.3123404906675f   // 12 * log2(e)

// ---------------------------------------------------------------------------
// Kernel 0: x[b,c,n] f32  ->  xt[b,n,c] bf16   (LDS tile transpose)
// ---------------------------------------------------------------------------
__global__ __launch_bounds__(256) void k_transpose(
    const float* __restrict__ x, __bf16* __restrict__ xt)
{
    __shared__ float tile[64][65];
    int bid = blockIdx.x;
    int b  = bid >> 8;
    int ct = (bid >> 6) & 3;
    int nt = bid & 63;
    int c0 = ct * 64, n0 = nt * 64;
    int t = threadIdx.x;

    const float* xb = x + (size_t)b * C_DIM * N_DIM;
#pragma unroll
    for (int k = 0; k < 16; k++) {
        int idx = k * 256 + t;
        int i = idx >> 6, j = idx & 63;
        tile[i][j] = xb[(size_t)(c0 + i) * N_DIM + n0 + j];
    }
    __syncthreads();
    __bf16* xtb = xt + (size_t)b * N_DIM * C_DIM;
#pragma unroll
    for (int k = 0; k < 16; k++) {
        int idx = k * 256 + t;
        int nl = idx >> 6, cl = idx & 63;
        xtb[(size_t)(n0 + nl) * C_DIM + c0 + cl] = (__bf16)tile[cl][nl];
    }
}

// ---------------------------------------------------------------------------
// Kernel 1: QKV projection. Q rows pre-scaled by log2(e).
// ---------------------------------------------------------------------------
__global__ __launch_bounds__(256) void k_qkv(
    const float* __restrict__ Wq, const float* __restrict__ bq,
    const float* __restrict__ Wk, const float* __restrict__ bk,
    const float* __restrict__ Wv, const float* __restrict__ bv,
    const __bf16* __restrict__ xt,
    __bf16* __restrict__ Qt, __bf16* __restrict__ Kt, __bf16* __restrict__ Vb)
{
    int bid = blockIdx.x;
    int b   = bid / 320;
    int rem = bid % 320;
    int dt  = rem / 64;
    int nt  = rem % 64;
    int n0  = nt * 64;
    int wid  = threadIdx.x >> 6;
    int lane = threadIdx.x & 63;
    int lg = lane >> 4, li = lane & 15;
    int d0w = dt * 64 + wid * 16;

    int drow = d0w + li;
    const float* wrow;
    if (drow < 32)        wrow = Wq + drow * C_DIM;
    else if (drow < 64)   wrow = Wk + (drow - 32) * C_DIM;
    else                  wrow = Wv + (drow - 64) * C_DIM;

    const __bf16* xtb = xt + (size_t)b * N_DIM * C_DIM;

    f32x4 acc[4] = {};
#pragma unroll
    for (int ks = 0; ks < 8; ks++) {
        int c0 = ks * 32 + lg * 8;
        float4 w0 = *(const float4*)(wrow + c0);
        float4 w1 = *(const float4*)(wrow + c0 + 4);
        bf16x8 af;
        af[0] = (__bf16)w0.x; af[1] = (__bf16)w0.y;
        af[2] = (__bf16)w0.z; af[3] = (__bf16)w0.w;
        af[4] = (__bf16)w1.x; af[5] = (__bf16)w1.y;
        af[6] = (__bf16)w1.z; af[7] = (__bf16)w1.w;
#pragma unroll
        for (int ns = 0; ns < 4; ns++) {
            bf16x8 bfr = *(const bf16x8*)(xtb + (size_t)(n0 + ns * 16 + li) * C_DIM + ks * 32 + lg * 8);
            acc[ns] = __builtin_amdgcn_mfma_f32_16x16x32_bf16(af, bfr, acc[ns], 0, 0, 0);
        }
    }
#pragma unroll
    for (int r = 0; r < 4; r++) {
        int d = d0w + lg * 4 + r;
        float bias = (d < 32) ? bq[d] : (d < 64) ? bk[d - 32] : bv[d - 64];
#pragma unroll
        for (int ns = 0; ns < 4; ns++) {
            int n = n0 + ns * 16 + li;
            float v = acc[ns][r] + bias;
            if (d < 32)
                Qt[((size_t)b * N_DIM + n) * C8 + d] = (__bf16)(v * LOG2E);
            else if (d < 64)
                Kt[((size_t)b * N_DIM + n) * C8 + (d - 32)] = (__bf16)v;
            else
                Vb[((size_t)b * C_DIM + (d - 64)) * N_DIM + n] = (__bf16)v;
        }
    }
}

// ---------------------------------------------------------------------------
// helpers for the barrier-free attention (layout verified in R7: absmax ok)
// ---------------------------------------------------------------------------
static __device__ __forceinline__ unsigned pack2(float a, float b) {
    union { __bf16 h[2]; unsigned u; } c;
    c.h[0] = (__bf16)a; c.h[1] = (__bf16)b; return c.u;
}
static __device__ __forceinline__ bf16x8 mkfrag(unsigned d0, unsigned d1, unsigned d2, unsigned d3) {
    union { unsigned u[4]; bf16x8 v; } r;
    r.u[0] = d0; r.u[1] = d1; r.u[2] = d2; r.u[3] = d3; return r.v;
}
static __device__ __forceinline__ uint2v plswap(unsigned a, unsigned b) {
#if __has_builtin(__builtin_amdgcn_permlane32_swap)
    return __builtin_amdgcn_permlane32_swap(a, b, false, false);
#else
    unsigned ax = (unsigned)__shfl_xor((int)a, 32);
    unsigned bx = (unsigned)__shfl_xor((int)b, 32);
    int hi = (threadIdx.x >> 5) & 1;
    uint2v r;
    r.x = hi ? bx : a;   // [a_lo | b_lo]
    r.y = hi ? b  : ax;  // [a_hi | b_hi]
    return r;
#endif
}
// S~ (K·Q^T) 32x32 C/D block -> exp2 -> two PV B-fragments (16-key slices).
static __device__ __forceinline__ void soft_pack(
    const f32x16& s, float& l, bf16x8& f0, bf16x8& f1)
{
    float p[16];
#pragma unroll
    for (int r = 0; r < 16; r++) p[r] = __builtin_amdgcn_exp2f(s[r] - SHIFT_L2);
    float lp = 0.f;
#pragma unroll
    for (int r = 0; r < 16; r++) lp += p[r];
    l += lp;
    unsigned a0 = pack2(p[0],  p[1]),  b0 = pack2(p[2],  p[3]);
    unsigned a1 = pack2(p[4],  p[5]),  b1 = pack2(p[6],  p[7]);
    unsigned a2 = pack2(p[8],  p[9]),  b2 = pack2(p[10], p[11]);
    unsigned a3 = pack2(p[12], p[13]), b3 = pack2(p[14], p[15]);
    uint2v rA0 = plswap(a0, a1), rB0 = plswap(b0, b1);
    uint2v rA1 = plswap(a2, a3), rB1 = plswap(b2, b3);
    f0 = mkfrag(rA0.x, rB0.x, rA0.y, rB0.y);   // keys 0..15
    f1 = mkfrag(rA1.x, rB1.x, rA1.y, rB1.y);   // keys 16..31
}

// ---------------------------------------------------------------------------
// Kernel 2: barrier-free flash attention, NON-redundant work split.
// Wave = 32 queries x 128 channels x 2048 keys. One soft_pack per 32-key
// step (exp redundancy only 2x from the channel split). Block = 4 waves =
// 4 adjacent query-tiles sharing identical K/V streams (L1-resident 8 KB
// V tile); batch b -> XCD b (bid%8), whose 2.3 MB K/V set fits the 4 MB L2.
// ---------------------------------------------------------------------------
__global__ __launch_bounds__(256, 3) void k_attn(
    const __bf16* __restrict__ Qt, const __bf16* __restrict__ Kt,
    const __bf16* __restrict__ Vb,
    __bf16* __restrict__ Op, float* __restrict__ Ll)
{
    int bid = blockIdx.x;
    int b   = bid & 7;            // batch -> XCD affinity
    int qt4 = (bid >> 3) & 31;    // group of 4 query-tiles
    int cs  = (bid >> 8) & 1;     // channel half
    int sp  = (bid >> 9) & 1;     // key half
    int wid = threadIdx.x >> 6;
    int li  = threadIdx.x & 31;
    int hi  = (threadIdx.x >> 5) & 1;
    int n0q = (qt4 * 4 + wid) * 32;
    int c0  = cs * 128;
    int m0s = sp * KEYS_PER;

    const __bf16* Qb  = Qt + (size_t)b * N_DIM * C8;
    const __bf16* Kb  = Kt + (size_t)b * N_DIM * C8;
    const __bf16* Vbb = Vb + (size_t)b * C_DIM * N_DIM;

    // Q B-frags (32 queries x 32 d), held whole kernel
    const __bf16* Ql = Qb + ((size_t)(n0q + li) << 5) + (hi << 3);
    bf16x8 qf0 = *(const bf16x8*)(Ql);        // d 0-15
    bf16x8 qf1 = *(const bf16x8*)(Ql + 16);   // d 16-31

    const __bf16* Kl = Kb + ((size_t)(m0s + li) << 5) + (hi << 3);
    const __bf16* Vl = Vbb + (size_t)(c0 + li) * N_DIM + m0s + hi * 8;

    f32x16 acc0 = {}, acc1 = {}, acc2 = {}, acc3 = {};   // 4 channel sub-tiles
    float l0 = 0.f;

    bf16x8 k0 = *(const bf16x8*)(Kl);
    bf16x8 k1 = *(const bf16x8*)(Kl + 16);

    for (int kb = 0; kb < KEYS_PER / 32; kb++) {
        int m0 = kb * 32;

        // S~ = K·Q^T : 32 keys x 32 queries (col = lane&31 = query)
        f32x16 z = {};
        f32x16 s = __builtin_amdgcn_mfma_f32_32x32x16_bf16(k0, qf0, z, 0, 0, 0);
        s = __builtin_amdgcn_mfma_f32_32x32x16_bf16(k1, qf1, s, 0, 0, 0);

        // prefetch next K block (hidden under soft_pack + PV)
        if (kb + 1 < KEYS_PER / 32) {
            k0 = *(const bf16x8*)(Kl + (kb + 1) * 1024);
            k1 = *(const bf16x8*)(Kl + (kb + 1) * 1024 + 16);
        }

        bf16x8 p0, p1;
        soft_pack(s, l0, p0, p1);

        // PV over 4 channel sub-tiles (V frags from L1-resident 8 KB tile)
        const __bf16* Vk = Vl + m0;
        {
            bf16x8 va = *(const bf16x8*)(Vk);
            bf16x8 vb_ = *(const bf16x8*)(Vk + 16);
            acc0 = __builtin_amdgcn_mfma_f32_32x32x16_bf16(va, p0, acc0, 0, 0, 0);
            acc0 = __builtin_amdgcn_mfma_f32_32x32x16_bf16(vb_, p1, acc0, 0, 0, 0);
        }
        {
            bf16x8 va = *(const bf16x8*)(Vk + (size_t)32 * N_DIM);
            bf16x8 vb_ = *(const bf16x8*)(Vk + (size_t)32 * N_DIM + 16);
            acc1 = __builtin_amdgcn_mfma_f32_32x32x16_bf16(va, p0, acc1, 0, 0, 0);
            acc1 = __builtin_amdgcn_mfma_f32_32x32x16_bf16(vb_, p1, acc1, 0, 0, 0);
        }
        {
            bf16x8 va = *(const bf16x8*)(Vk + (size_t)64 * N_DIM);
            bf16x8 vb_ = *(const bf16x8*)(Vk + (size_t)64 * N_DIM + 16);
            acc2 = __builtin_amdgcn_mfma_f32_32x32x16_bf16(va, p0, acc2, 0, 0, 0);
            acc2 = __builtin_amdgcn_mfma_f32_32x32x16_bf16(vb_, p1, acc2, 0, 0, 0);
        }
        {
            bf16x8 va = *(const bf16x8*)(Vk + (size_t)96 * N_DIM);
            bf16x8 vb_ = *(const bf16x8*)(Vk + (size_t)96 * N_DIM + 16);
            acc3 = __builtin_amdgcn_mfma_f32_32x32x16_bf16(va, p0, acc3, 0, 0, 0);
            acc3 = __builtin_amdgcn_mfma_f32_32x32x16_bf16(vb_, p1, acc3, 0, 0, 0);
        }
    }

    // ---- epilogue: l (cross-hi reduce) + partial O
    size_t sb = (size_t)(sp * B_DIM + b);
    float lv = l0 + __shfl_xor(l0, 32);
    if (cs == 0 && hi == 0)
        Ll[sb * N_DIM + n0q + li] = lv;

#define STORE_ACC(A, CS4)                                                      \
    _Pragma("unroll")                                                          \
    for (int rg = 0; rg < 16; rg++) {                                          \
        int row = (rg & 3) + 8 * (rg >> 2) + 4 * hi;                           \
        Op[((size_t)sb * C_DIM + (c0 + CS4 * 32 + row)) * N_DIM               \
           + (n0q + li)] = (__bf16)A[rg];                                      \
    }
    STORE_ACC(acc0, 0)
    STORE_ACC(acc1, 1)
    STORE_ACC(acc2, 2)
    STORE_ACC(acc3, 3)
#undef STORE_ACC
}

// ---------------------------------------------------------------------------
// Kernel 3: combine (sum partials, one gamma/L multiply, residual)
// ---------------------------------------------------------------------------
__global__ __launch_bounds__(256) void k_combine(
    const float* __restrict__ x, const __bf16* __restrict__ Op,
    const float* __restrict__ Ll,
    const float* __restrict__ gamma, float* __restrict__ out)
{
    int tid = blockIdx.x * 256 + threadIdx.x;   // 131072 total
    int n4 = tid & 1023;
    int cg = (tid >> 10) & 15;
    int b  = tid >> 14;
    int n  = n4 * 4;
    float g = gamma[0];

    float inv[4];
    {
        float L[4] = {0.f, 0.f, 0.f, 0.f};
#pragma unroll
        for (int s = 0; s < SPLIT; s++) {
            float4 t1 = *(const float4*)(Ll + ((size_t)(s * B_DIM + b) << 12) + n);
            L[0] += t1.x; L[1] += t1.y; L[2] += t1.z; L[3] += t1.w;
        }
#pragma unroll
        for (int j = 0; j < 4; j++) inv[j] = g / L[j];
    }

#pragma unroll 4
    for (int ci = 0; ci < 16; ci++) {
        int c = cg * 16 + ci;
        size_t base = (((size_t)b * C_DIM + c) << 12) + n;
        float4 xv = *(const float4*)(x + base);
        float o0 = 0.f, o1 = 0.f, o2 = 0.f, o3 = 0.f;
#pragma unroll
        for (int s = 0; s < SPLIT; s++) {
            bf16x4 p = *(const bf16x4*)(Op + (((size_t)(s * B_DIM + b) * C_DIM + c) << 12) + n);
            o0 += (float)p[0];
            o1 += (float)p[1];
            o2 += (float)p[2];
            o3 += (float)p[3];
        }
        float4 ov = { xv.x + o0 * inv[0], xv.y + o1 * inv[1],
                      xv.z + o2 * inv[2], xv.w + o3 * inv[3] };
        *(float4*)(out + base) = ov;
    }
}

// ---------------------------------------------------------------------------
extern "C" void kernel_launch(void* const* d_in, const int* in_sizes, int n_in,
                              void* d_out, int out_size, void* d_ws, size_t ws_size,
                              hipStream_t stream)
{
    const float* x     = (const float*)d_in[0];
    const float* Wq    = (const float*)d_in[1];
    const float* bq    = (const float*)d_in[2];
    const float* Wk    = (const float*)d_in[3];
    const float* bk    = (const float*)d_in[4];
    const float* Wv    = (const float*)d_in[5];
    const float* bv    = (const float*)d_in[6];
    const float* gamma = (const float*)d_in[7];
    float* out = (float*)d_out;

    char* ws = (char*)d_ws;
    const size_t MB = 1024 * 1024;
    __bf16* xt = (__bf16*)ws;                      // 16 MiB
    __bf16* Qt = (__bf16*)(ws + 16 * MB);          //  2 MiB
    __bf16* Kt = (__bf16*)(ws + 18 * MB);          //  2 MiB
    __bf16* Vb = (__bf16*)(ws + 20 * MB);          // 16 MiB
    __bf16* Op = (__bf16*)(ws + 36 * MB);          // 32 MiB (2 key-splits)
    float*  Ll = (float*)(ws + 100 * MB);          // 256 KiB

    k_transpose<<<2048, 256, 0, stream>>>(x, xt);
    k_qkv<<<2560, 256, 0, stream>>>(Wq, bq, Wk, bk, Wv, bv, xt, Qt, Kt, Vb);
    k_attn<<<1024, 256, 0, stream>>>(Qt, Kt, Vb, Op, Ll);
    k_combine<<<512, 256, 0, stream>>>(x, Op, Ll, gamma, out);
}

// Round 9
// 331.486 us; speedup vs baseline: 1.0406x; 1.0406x over previous
//
#include <hip/hip_runtime.h>
#include <hip/hip_bf16.h>

#define C_DIM 256
#define C8 32
#define N_DIM 4096
#define B_DIM 8
#define NSTEP (N_DIM / 32)   // 128 key-steps of 32

using bf16x8 = __attribute__((ext_vector_type(8))) __bf16;
using bf16x4 = __attribute__((ext_vector_type(4))) __bf16;
using f32x4  = __attribute__((ext_vector_type(4))) float;
using f32x16 = __attribute__((ext_vector_type(16))) float;
using uint2v = __attribute__((ext_vector_type(2))) unsigned;

#define LOG2E 1.44269504088896f
#define SHIFT_L2 17.3123404906675f   // 12 * log2(e)

// ---------------------------------------------------------------------------
// Kernel 0: x[b,c,n] f32  ->  xt[b,n,c] bf16   (LDS tile transpose)
// ---------------------------------------------------------------------------
__global__ __launch_bounds__(256) void k_transpose(
    const float* __restrict__ x, __bf16* __restrict__ xt)
{
    __shared__ float tile[64][65];
    int bid = blockIdx.x;
    int b  = bid >> 8;
    int ct = (bid >> 6) & 3;
    int nt = bid & 63;
    int c0 = ct * 64, n0 = nt * 64;
    int t = threadIdx.x;

    const float* xb = x + (size_t)b * C_DIM * N_DIM;
#pragma unroll
    for (int k = 0; k < 16; k++) {
        int idx = k * 256 + t;
        int i = idx >> 6, j = idx & 63;
        tile[i][j] = xb[(size_t)(c0 + i) * N_DIM + n0 + j];
    }
    __syncthreads();
    __bf16* xtb = xt + (size_t)b * N_DIM * C_DIM;
#pragma unroll
    for (int k = 0; k < 16; k++) {
        int idx = k * 256 + t;
        int nl = idx >> 6, cl = idx & 63;
        xtb[(size_t)(n0 + nl) * C_DIM + c0 + cl] = (__bf16)tile[cl][nl];
    }
}

// ---------------------------------------------------------------------------
// Kernel 1: QKV projection. Q rows pre-scaled by log2(e).
// ---------------------------------------------------------------------------
__global__ __launch_bounds__(256) void k_qkv(
    const float* __restrict__ Wq, const float* __restrict__ bq,
    const float* __restrict__ Wk, const float* __restrict__ bk,
    const float* __restrict__ Wv, const float* __restrict__ bv,
    const __bf16* __restrict__ xt,
    __bf16* __restrict__ Qt, __bf16* __restrict__ Kt, __bf16* __restrict__ Vb)
{
    int bid = blockIdx.x;
    int b   = bid / 320;
    int rem = bid % 320;
    int dt  = rem / 64;
    int nt  = rem % 64;
    int n0  = nt * 64;
    int wid  = threadIdx.x >> 6;
    int lane = threadIdx.x & 63;
    int lg = lane >> 4, li = lane & 15;
    int d0w = dt * 64 + wid * 16;

    int drow = d0w + li;
    const float* wrow;
    if (drow < 32)        wrow = Wq + drow * C_DIM;
    else if (drow < 64)   wrow = Wk + (drow - 32) * C_DIM;
    else                  wrow = Wv + (drow - 64) * C_DIM;

    const __bf16* xtb = xt + (size_t)b * N_DIM * C_DIM;

    f32x4 acc[4] = {};
#pragma unroll
    for (int ks = 0; ks < 8; ks++) {
        int c0 = ks * 32 + lg * 8;
        float4 w0 = *(const float4*)(wrow + c0);
        float4 w1 = *(const float4*)(wrow + c0 + 4);
        bf16x8 af;
        af[0] = (__bf16)w0.x; af[1] = (__bf16)w0.y;
        af[2] = (__bf16)w0.z; af[3] = (__bf16)w0.w;
        af[4] = (__bf16)w1.x; af[5] = (__bf16)w1.y;
        af[6] = (__bf16)w1.z; af[7] = (__bf16)w1.w;
#pragma unroll
        for (int ns = 0; ns < 4; ns++) {
            bf16x8 bfr = *(const bf16x8*)(xtb + (size_t)(n0 + ns * 16 + li) * C_DIM + ks * 32 + lg * 8);
            acc[ns] = __builtin_amdgcn_mfma_f32_16x16x32_bf16(af, bfr, acc[ns], 0, 0, 0);
        }
    }
#pragma unroll
    for (int r = 0; r < 4; r++) {
        int d = d0w + lg * 4 + r;
        float bias = (d < 32) ? bq[d] : (d < 64) ? bk[d - 32] : bv[d - 64];
#pragma unroll
        for (int ns = 0; ns < 4; ns++) {
            int n = n0 + ns * 16 + li;
            float v = acc[ns][r] + bias;
            if (d < 32)
                Qt[((size_t)b * N_DIM + n) * C8 + d] = (__bf16)(v * LOG2E);
            else if (d < 64)
                Kt[((size_t)b * N_DIM + n) * C8 + (d - 32)] = (__bf16)v;
            else
                Vb[((size_t)b * C_DIM + (d - 64)) * N_DIM + n] = (__bf16)v;
        }
    }
}

// ---------------------------------------------------------------------------
// helpers (layout verified in R7/R8: absmax matched reference)
// ---------------------------------------------------------------------------
static __device__ __forceinline__ unsigned pack2(float a, float b) {
    union { __bf16 h[2]; unsigned u; } c;
    c.h[0] = (__bf16)a; c.h[1] = (__bf16)b; return c.u;
}
static __device__ __forceinline__ bf16x8 mkfrag(unsigned d0, unsigned d1, unsigned d2, unsigned d3) {
    union { unsigned u[4]; bf16x8 v; } r;
    r.u[0] = d0; r.u[1] = d1; r.u[2] = d2; r.u[3] = d3; return r.v;
}
static __device__ __forceinline__ uint2v plswap(unsigned a, unsigned b) {
#if __has_builtin(__builtin_amdgcn_permlane32_swap)
    return __builtin_amdgcn_permlane32_swap(a, b, false, false);
#else
    unsigned ax = (unsigned)__shfl_xor((int)a, 32);
    unsigned bx = (unsigned)__shfl_xor((int)b, 32);
    int hi = (threadIdx.x >> 5) & 1;
    uint2v r;
    r.x = hi ? bx : a;
    r.y = hi ? b  : ax;
    return r;
#endif
}
// S~ (K·Q^T) 32x32 C/D block -> exp2 -> two PV B-fragments (16-key slices).
static __device__ __forceinline__ void soft_pack(
    const f32x16& s, float& l, bf16x8& f0, bf16x8& f1)
{
    float p[16];
#pragma unroll
    for (int r = 0; r < 16; r++) p[r] = __builtin_amdgcn_exp2f(s[r] - SHIFT_L2);
    float lp = 0.f;
#pragma unroll
    for (int r = 0; r < 16; r++) lp += p[r];
    l += lp;
    unsigned a0 = pack2(p[0],  p[1]),  b0 = pack2(p[2],  p[3]);
    unsigned a1 = pack2(p[4],  p[5]),  b1 = pack2(p[6],  p[7]);
    unsigned a2 = pack2(p[8],  p[9]),  b2 = pack2(p[10], p[11]);
    unsigned a3 = pack2(p[12], p[13]), b3 = pack2(p[14], p[15]);
    uint2v rA0 = plswap(a0, a1), rB0 = plswap(b0, b1);
    uint2v rA1 = plswap(a2, a3), rB1 = plswap(b2, b3);
    f0 = mkfrag(rA0.x, rB0.x, rA0.y, rB0.y);   // keys 0..15
    f1 = mkfrag(rA1.x, rB1.x, rA1.y, rB1.y);   // keys 16..31
}

// ---------------------------------------------------------------------------
// Kernel 2: barrier-free full-softmax flash attention + fused epilogue.
// Wave = 32 queries x 128 channels x ALL 4096 keys (no key split -> no
// combine pass). Explicit double-buffered K(2 frags) + V(8 frags) prefetch:
// next step's loads issue at step top, consumed next iteration (~full-step
// load-use distance). Block = 4 waves = 4 adjacent query-tiles sharing the
// same K/V stream (L1 reuse); b = bid&7 keeps batch K/V on one XCD's L2.
// Epilogue: out = gamma * acc / l + x  (direct, f32).
// ---------------------------------------------------------------------------
__global__ __launch_bounds__(256, 2) void k_attn(
    const __bf16* __restrict__ Qt, const __bf16* __restrict__ Kt,
    const __bf16* __restrict__ Vb, const float* __restrict__ x,
    const float* __restrict__ gamma, float* __restrict__ out)
{
    int bid = blockIdx.x;            // 512 blocks
    int b   = bid & 7;               // batch -> XCD affinity
    int qt4 = (bid >> 3) & 31;       // group of 4 query-tiles
    int cs  = (bid >> 8) & 1;        // channel half
    int wid = threadIdx.x >> 6;
    int li  = threadIdx.x & 31;
    int hi  = (threadIdx.x >> 5) & 1;
    int n0q = (qt4 * 4 + wid) * 32;
    int c0  = cs * 128;

    const __bf16* Qb  = Qt + (size_t)b * N_DIM * C8;
    const __bf16* Kb  = Kt + (size_t)b * N_DIM * C8;
    const __bf16* Vbb = Vb + (size_t)b * C_DIM * N_DIM;

    // Q B-frags (32 queries x 32 d), held whole kernel
    const __bf16* Ql = Qb + ((size_t)(n0q + li) << 5) + (hi << 3);
    bf16x8 qf0 = *(const bf16x8*)(Ql);        // d 0-15
    bf16x8 qf1 = *(const bf16x8*)(Ql + 16);   // d 16-31

    const __bf16* Kl = Kb + ((size_t)li << 5) + (hi << 3);
    const __bf16* Vl = Vbb + (size_t)(c0 + li) * N_DIM + hi * 8;

    f32x16 acc0 = {}, acc1 = {}, acc2 = {}, acc3 = {};
    float l0 = 0.f;

    // double-buffered operands
    bf16x8 kA0, kA1, kB0, kB1;
    bf16x8 vA[8], vB[8];

    // prologue: load step 0 into A
    kA0 = *(const bf16x8*)(Kl);
    kA1 = *(const bf16x8*)(Kl + 16);
#pragma unroll
    for (int f = 0; f < 8; f++) {
        int ct = f >> 1, ks = f & 1;
        vA[f] = *(const bf16x8*)(Vl + (size_t)(ct * 32) * N_DIM + ks * 16);
    }

    // STEP: prefetch step I+1 into N-buffers, compute step I from C-buffers
#define STEP(CK0, CK1, CV, NK0, NK1, NV, I)                                    \
    {                                                                          \
        int ni = ((I) + 1 < NSTEP) ? (I) + 1 : (I);                            \
        NK0 = *(const bf16x8*)(Kl + (size_t)ni * 1024);                        \
        NK1 = *(const bf16x8*)(Kl + (size_t)ni * 1024 + 16);                   \
        const __bf16* Vn = Vl + ni * 32;                                       \
        NV[0] = *(const bf16x8*)(Vn);                                          \
        NV[1] = *(const bf16x8*)(Vn + 16);                                     \
        NV[2] = *(const bf16x8*)(Vn + (size_t)32 * N_DIM);                     \
        NV[3] = *(const bf16x8*)(Vn + (size_t)32 * N_DIM + 16);                \
        NV[4] = *(const bf16x8*)(Vn + (size_t)64 * N_DIM);                     \
        NV[5] = *(const bf16x8*)(Vn + (size_t)64 * N_DIM + 16);                \
        NV[6] = *(const bf16x8*)(Vn + (size_t)96 * N_DIM);                     \
        NV[7] = *(const bf16x8*)(Vn + (size_t)96 * N_DIM + 16);                \
        f32x16 z = {};                                                         \
        f32x16 s = __builtin_amdgcn_mfma_f32_32x32x16_bf16(CK0, qf0, z, 0, 0, 0); \
        s = __builtin_amdgcn_mfma_f32_32x32x16_bf16(CK1, qf1, s, 0, 0, 0);     \
        bf16x8 p0, p1;                                                         \
        soft_pack(s, l0, p0, p1);                                              \
        acc0 = __builtin_amdgcn_mfma_f32_32x32x16_bf16(CV[0], p0, acc0, 0, 0, 0); \
        acc0 = __builtin_amdgcn_mfma_f32_32x32x16_bf16(CV[1], p1, acc0, 0, 0, 0); \
        acc1 = __builtin_amdgcn_mfma_f32_32x32x16_bf16(CV[2], p0, acc1, 0, 0, 0); \
        acc1 = __builtin_amdgcn_mfma_f32_32x32x16_bf16(CV[3], p1, acc1, 0, 0, 0); \
        acc2 = __builtin_amdgcn_mfma_f32_32x32x16_bf16(CV[4], p0, acc2, 0, 0, 0); \
        acc2 = __builtin_amdgcn_mfma_f32_32x32x16_bf16(CV[5], p1, acc2, 0, 0, 0); \
        acc3 = __builtin_amdgcn_mfma_f32_32x32x16_bf16(CV[6], p0, acc3, 0, 0, 0); \
        acc3 = __builtin_amdgcn_mfma_f32_32x32x16_bf16(CV[7], p1, acc3, 0, 0, 0); \
    }

    for (int i = 0; i < NSTEP; i += 2) {
        STEP(kA0, kA1, vA, kB0, kB1, vB, i)
        STEP(kB0, kB1, vB, kA0, kA1, vA, i + 1)
    }
#undef STEP

    // ---- epilogue: l reduce across hi halves, direct out write + residual
    float lv = l0 + __shfl_xor(l0, 32);
    float g = gamma[0];
    float linv = g / lv;

#define STORE_ACC(A, CT)                                                       \
    _Pragma("unroll")                                                          \
    for (int rg = 0; rg < 16; rg++) {                                          \
        int row = (rg & 3) + 8 * (rg >> 2) + 4 * hi;                           \
        size_t idx = ((size_t)b * C_DIM + (c0 + CT * 32 + row)) * N_DIM        \
                     + (n0q + li);                                             \
        out[idx] = A[rg] * linv + x[idx];                                      \
    }
    STORE_ACC(acc0, 0)
    STORE_ACC(acc1, 1)
    STORE_ACC(acc2, 2)
    STORE_ACC(acc3, 3)
#undef STORE_ACC
}

// ---------------------------------------------------------------------------
extern "C" void kernel_launch(void* const* d_in, const int* in_sizes, int n_in,
                              void* d_out, int out_size, void* d_ws, size_t ws_size,
                              hipStream_t stream)
{
    const float* x     = (const float*)d_in[0];
    const float* Wq    = (const float*)d_in[1];
    const float* bq    = (const float*)d_in[2];
    const float* Wk    = (const float*)d_in[3];
    const float* bk    = (const float*)d_in[4];
    const float* Wv    = (const float*)d_in[5];
    const float* bv    = (const float*)d_in[6];
    const float* gamma = (const float*)d_in[7];
    float* out = (float*)d_out;

    char* ws = (char*)d_ws;
    const size_t MB = 1024 * 1024;
    __bf16* xt = (__bf16*)ws;                      // 16 MiB
    __bf16* Qt = (__bf16*)(ws + 16 * MB);          //  2 MiB
    __bf16* Kt = (__bf16*)(ws + 18 * MB);          //  2 MiB
    __bf16* Vb = (__bf16*)(ws + 20 * MB);          // 16 MiB

    k_transpose<<<2048, 256, 0, stream>>>(x, xt);
    k_qkv<<<2560, 256, 0, stream>>>(Wq, bq, Wk, bk, Wv, bv, xt, Qt, Kt, Vb);
    k_attn<<<512, 256, 0, stream>>>(Qt, Kt, Vb, x, gamma, out);
}

// Round 10
// 217.725 us; speedup vs baseline: 1.5843x; 1.5225x over previous
//
#include <hip/hip_runtime.h>
#include <hip/hip_bf16.h>

#define C_DIM 256
#define C8 32
#define N_DIM 4096
#define B_DIM 8
#define NSTEP (N_DIM / 32)   // 128 key-steps of 32

using bf16x8 = __attribute__((ext_vector_type(8))) __bf16;
using f32x4  = __attribute__((ext_vector_type(4))) float;
using f32x16 = __attribute__((ext_vector_type(16))) float;
using uint2v = __attribute__((ext_vector_type(2))) unsigned;

#define LOG2E 1.44269504088896f
#define SHIFT_L2 17.3123404906675f   // 12 * log2(e)

// Tiled layouts (fragment-major, per batch):
//   Q/K: idx(n,d) = (n>>5)*1024 + (d>>3)*256 + (n&31)*8 + (d&7)    [N*32 elems]
//   V  : idx(c,n) = (n>>4)*4096 + ((n>>3)&1)*2048 + c*8 + (n&7)    [N*C elems]
// A wave's fragment load is then 1-2 contiguous 512B segments instead of a
// 16-32 cache-line gather.

// ---------------------------------------------------------------------------
// Kernel 0: x[b,c,n] f32  ->  xt[b,n,c] bf16   (LDS tile transpose)
// ---------------------------------------------------------------------------
__global__ __launch_bounds__(256) void k_transpose(
    const float* __restrict__ x, __bf16* __restrict__ xt)
{
    __shared__ float tile[64][65];
    int bid = blockIdx.x;
    int b  = bid >> 8;
    int ct = (bid >> 6) & 3;
    int nt = bid & 63;
    int c0 = ct * 64, n0 = nt * 64;
    int t = threadIdx.x;

    const float* xb = x + (size_t)b * C_DIM * N_DIM;
#pragma unroll
    for (int k = 0; k < 16; k++) {
        int idx = k * 256 + t;
        int i = idx >> 6, j = idx & 63;
        tile[i][j] = xb[(size_t)(c0 + i) * N_DIM + n0 + j];
    }
    __syncthreads();
    __bf16* xtb = xt + (size_t)b * N_DIM * C_DIM;
#pragma unroll
    for (int k = 0; k < 16; k++) {
        int idx = k * 256 + t;
        int nl = idx >> 6, cl = idx & 63;
        xtb[(size_t)(n0 + nl) * C_DIM + c0 + cl] = (__bf16)tile[cl][nl];
    }
}

// ---------------------------------------------------------------------------
// Kernel 1: QKV projection -> TILED outputs. Q pre-scaled by log2(e).
// ---------------------------------------------------------------------------
__global__ __launch_bounds__(256) void k_qkv(
    const float* __restrict__ Wq, const float* __restrict__ bq,
    const float* __restrict__ Wk, const float* __restrict__ bk,
    const float* __restrict__ Wv, const float* __restrict__ bv,
    const __bf16* __restrict__ xt,
    __bf16* __restrict__ Qt, __bf16* __restrict__ Kt, __bf16* __restrict__ Vb)
{
    int bid = blockIdx.x;
    int b   = bid / 320;
    int rem = bid % 320;
    int dt  = rem / 64;
    int nt  = rem % 64;
    int n0  = nt * 64;
    int wid  = threadIdx.x >> 6;
    int lane = threadIdx.x & 63;
    int lg = lane >> 4, li = lane & 15;
    int d0w = dt * 64 + wid * 16;

    int drow = d0w + li;
    const float* wrow;
    if (drow < 32)        wrow = Wq + drow * C_DIM;
    else if (drow < 64)   wrow = Wk + (drow - 32) * C_DIM;
    else                  wrow = Wv + (drow - 64) * C_DIM;

    const __bf16* xtb = xt + (size_t)b * N_DIM * C_DIM;

    f32x4 acc[4] = {};
#pragma unroll
    for (int ks = 0; ks < 8; ks++) {
        int c0 = ks * 32 + lg * 8;
        float4 w0 = *(const float4*)(wrow + c0);
        float4 w1 = *(const float4*)(wrow + c0 + 4);
        bf16x8 af;
        af[0] = (__bf16)w0.x; af[1] = (__bf16)w0.y;
        af[2] = (__bf16)w0.z; af[3] = (__bf16)w0.w;
        af[4] = (__bf16)w1.x; af[5] = (__bf16)w1.y;
        af[6] = (__bf16)w1.z; af[7] = (__bf16)w1.w;
#pragma unroll
        for (int ns = 0; ns < 4; ns++) {
            bf16x8 bfr = *(const bf16x8*)(xtb + (size_t)(n0 + ns * 16 + li) * C_DIM + ks * 32 + lg * 8);
            acc[ns] = __builtin_amdgcn_mfma_f32_16x16x32_bf16(af, bfr, acc[ns], 0, 0, 0);
        }
    }
    __bf16* Qtb = Qt + (size_t)b * (N_DIM * 32);
    __bf16* Ktb = Kt + (size_t)b * (N_DIM * 32);
    __bf16* Vtb = Vb + (size_t)b * (N_DIM * C_DIM);
#pragma unroll
    for (int r = 0; r < 4; r++) {
        int d = d0w + lg * 4 + r;
        float bias = (d < 32) ? bq[d] : (d < 64) ? bk[d - 32] : bv[d - 64];
#pragma unroll
        for (int ns = 0; ns < 4; ns++) {
            int n = n0 + ns * 16 + li;
            float v = acc[ns][r] + bias;
            if (d < 32) {
                int dd = d;
                Qtb[((n >> 5) << 10) + ((dd >> 3) << 8) + ((n & 31) << 3) + (dd & 7)]
                    = (__bf16)(v * LOG2E);
            } else if (d < 64) {
                int dd = d - 32;
                Ktb[((n >> 5) << 10) + ((dd >> 3) << 8) + ((n & 31) << 3) + (dd & 7)]
                    = (__bf16)v;
            } else {
                int c = d - 64;
                Vtb[((n >> 4) << 12) + (((n >> 3) & 1) << 11) + (c << 3) + (n & 7)]
                    = (__bf16)v;
            }
        }
    }
}

// ---------------------------------------------------------------------------
// helpers (numerics verified R7-R9: absmax matched)
// ---------------------------------------------------------------------------
static __device__ __forceinline__ unsigned pack2(float a, float b) {
    union { __bf16 h[2]; unsigned u; } c;
    c.h[0] = (__bf16)a; c.h[1] = (__bf16)b; return c.u;
}
static __device__ __forceinline__ bf16x8 mkfrag(unsigned d0, unsigned d1, unsigned d2, unsigned d3) {
    union { unsigned u[4]; bf16x8 v; } r;
    r.u[0] = d0; r.u[1] = d1; r.u[2] = d2; r.u[3] = d3; return r.v;
}
static __device__ __forceinline__ uint2v plswap(unsigned a, unsigned b) {
#if __has_builtin(__builtin_amdgcn_permlane32_swap)
    return __builtin_amdgcn_permlane32_swap(a, b, false, false);
#else
    unsigned ax = (unsigned)__shfl_xor((int)a, 32);
    unsigned bx = (unsigned)__shfl_xor((int)b, 32);
    int hi = (threadIdx.x >> 5) & 1;
    uint2v r;
    r.x = hi ? bx : a;
    r.y = hi ? b  : ax;
    return r;
#endif
}
// S~ (K·Q^T) 32x32 C/D block -> exp2 -> two PV B-fragments (16-key slices).
static __device__ __forceinline__ void soft_pack(
    const f32x16& s, float& l, bf16x8& f0, bf16x8& f1)
{
    float p[16];
#pragma unroll
    for (int r = 0; r < 16; r++) p[r] = __builtin_amdgcn_exp2f(s[r] - SHIFT_L2);
    float lp = 0.f;
#pragma unroll
    for (int r = 0; r < 16; r++) lp += p[r];
    l += lp;
    unsigned a0 = pack2(p[0],  p[1]),  b0 = pack2(p[2],  p[3]);
    unsigned a1 = pack2(p[4],  p[5]),  b1 = pack2(p[6],  p[7]);
    unsigned a2 = pack2(p[8],  p[9]),  b2 = pack2(p[10], p[11]);
    unsigned a3 = pack2(p[12], p[13]), b3 = pack2(p[14], p[15]);
    uint2v rA0 = plswap(a0, a1), rB0 = plswap(b0, b1);
    uint2v rA1 = plswap(a2, a3), rB1 = plswap(b2, b3);
    f0 = mkfrag(rA0.x, rB0.x, rA0.y, rB0.y);   // keys 0..15
    f1 = mkfrag(rA1.x, rB1.x, rA1.y, rB1.y);   // keys 16..31
}

// ---------------------------------------------------------------------------
// Kernel 2: barrier-free full-softmax flash attention, TILED operands.
// Wave = 32 queries x 64 channels x all 4096 keys -> 4096 waves (1024 blocks,
// 4 waves/SIMD at <=128 VGPR). All fragment loads are 1-2 contiguous 512B
// segments. Double-buffered K(2)+V(4) prefetch one step ahead. Block's 4
// waves = 4 adjacent query-tiles sharing the same K/V stream (L1 reuse);
// b = bid&7 keeps each batch's K/V on one XCD's L2. Fused epilogue.
// ---------------------------------------------------------------------------
__global__ __launch_bounds__(256, 4) void k_attn(
    const __bf16* __restrict__ Qt, const __bf16* __restrict__ Kt,
    const __bf16* __restrict__ Vb, const float* __restrict__ x,
    const float* __restrict__ gamma, float* __restrict__ out)
{
    int bid = blockIdx.x;            // 1024 blocks
    int b   = bid & 7;               // batch -> XCD affinity
    int cs  = (bid >> 3) & 3;        // channel quarter (64 ch)
    int qg  = bid >> 5;              // 0..31 : group of 4 query-tiles
    int wid = threadIdx.x >> 6;
    int li  = threadIdx.x & 31;
    int hi  = (threadIdx.x >> 5) & 1;
    int n0q = (qg * 4 + wid) * 32;
    int c0  = cs * 64;

    const __bf16* Qtb = Qt + (size_t)b * (N_DIM * 32);
    const __bf16* Ktb = Kt + (size_t)b * (N_DIM * 32);
    const __bf16* Vtb = Vb + (size_t)b * (N_DIM * C_DIM);

    // Q B-frags (32 queries x 32 d), contiguous 1KB loads
    const __bf16* Qlp = Qtb + ((n0q >> 5) << 10) + (hi << 8) + (li << 3);
    bf16x8 qf0 = *(const bf16x8*)(Qlp);        // d 0-15
    bf16x8 qf1 = *(const bf16x8*)(Qlp + 512);  // d 16-31

    const __bf16* Klp = Ktb + (hi << 8) + (li << 3);
    const __bf16* Vlp = Vtb + (hi << 11) + ((c0 + li) << 3);

    f32x16 acc0 = {}, acc1 = {};
    float l0 = 0.f;

    bf16x8 kA0, kA1, kB0, kB1;
    bf16x8 vA[4], vB[4];

    // prologue: step 0 into A
    kA0 = *(const bf16x8*)(Klp);
    kA1 = *(const bf16x8*)(Klp + 512);
    vA[0] = *(const bf16x8*)(Vlp);
    vA[1] = *(const bf16x8*)(Vlp + 256);
    vA[2] = *(const bf16x8*)(Vlp + 4096);
    vA[3] = *(const bf16x8*)(Vlp + 4096 + 256);

#define STEP(CK0, CK1, CV, NK0, NK1, NV, I)                                    \
    {                                                                          \
        int ni = ((I) + 1 < NSTEP) ? (I) + 1 : (I);                            \
        const __bf16* Kn = Klp + ((size_t)ni << 10);                           \
        NK0 = *(const bf16x8*)(Kn);                                            \
        NK1 = *(const bf16x8*)(Kn + 512);                                      \
        const __bf16* Vn = Vlp + ((size_t)ni << 13);                           \
        NV[0] = *(const bf16x8*)(Vn);                                          \
        NV[1] = *(const bf16x8*)(Vn + 256);                                    \
        NV[2] = *(const bf16x8*)(Vn + 4096);                                   \
        NV[3] = *(const bf16x8*)(Vn + 4096 + 256);                             \
        f32x16 z = {};                                                         \
        __builtin_amdgcn_s_setprio(1);                                         \
        f32x16 s = __builtin_amdgcn_mfma_f32_32x32x16_bf16(CK0, qf0, z, 0, 0, 0); \
        s = __builtin_amdgcn_mfma_f32_32x32x16_bf16(CK1, qf1, s, 0, 0, 0);     \
        __builtin_amdgcn_s_setprio(0);                                         \
        bf16x8 p0, p1;                                                         \
        soft_pack(s, l0, p0, p1);                                              \
        __builtin_amdgcn_s_setprio(1);                                         \
        acc0 = __builtin_amdgcn_mfma_f32_32x32x16_bf16(CV[0], p0, acc0, 0, 0, 0); \
        acc1 = __builtin_amdgcn_mfma_f32_32x32x16_bf16(CV[1], p0, acc1, 0, 0, 0); \
        acc0 = __builtin_amdgcn_mfma_f32_32x32x16_bf16(CV[2], p1, acc0, 0, 0, 0); \
        acc1 = __builtin_amdgcn_mfma_f32_32x32x16_bf16(CV[3], p1, acc1, 0, 0, 0); \
        __builtin_amdgcn_s_setprio(0);                                         \
    }

    for (int i = 0; i < NSTEP; i += 2) {
        STEP(kA0, kA1, vA, kB0, kB1, vB, i)
        STEP(kB0, kB1, vB, kA0, kA1, vA, i + 1)
    }
#undef STEP

    // ---- epilogue: l reduce across hi halves, fused gamma/l + residual
    float lv = l0 + __shfl_xor(l0, 32);
    float linv = gamma[0] / lv;

#define STORE_ACC(A, G)                                                        \
    _Pragma("unroll")                                                          \
    for (int rg = 0; rg < 16; rg++) {                                          \
        int row = (rg & 3) + 8 * (rg >> 2) + 4 * hi;                           \
        size_t idx = ((size_t)b * C_DIM + (c0 + (G) * 32 + row)) * N_DIM       \
                     + (n0q + li);                                             \
        out[idx] = A[rg] * linv + x[idx];                                      \
    }
    STORE_ACC(acc0, 0)
    STORE_ACC(acc1, 1)
#undef STORE_ACC
}

// ---------------------------------------------------------------------------
extern "C" void kernel_launch(void* const* d_in, const int* in_sizes, int n_in,
                              void* d_out, int out_size, void* d_ws, size_t ws_size,
                              hipStream_t stream)
{
    const float* x     = (const float*)d_in[0];
    const float* Wq    = (const float*)d_in[1];
    const float* bq    = (const float*)d_in[2];
    const float* Wk    = (const float*)d_in[3];
    const float* bk    = (const float*)d_in[4];
    const float* Wv    = (const float*)d_in[5];
    const float* bv    = (const float*)d_in[6];
    const float* gamma = (const float*)d_in[7];
    float* out = (float*)d_out;

    char* ws = (char*)d_ws;
    const size_t MB = 1024 * 1024;
    __bf16* xt = (__bf16*)ws;                      // 16 MiB
    __bf16* Qt = (__bf16*)(ws + 16 * MB);          //  2 MiB (tiled)
    __bf16* Kt = (__bf16*)(ws + 18 * MB);          //  2 MiB (tiled)
    __bf16* Vb = (__bf16*)(ws + 20 * MB);          // 16 MiB (tiled)

    k_transpose<<<2048, 256, 0, stream>>>(x, xt);
    k_qkv<<<2560, 256, 0, stream>>>(Wq, bq, Wk, bk, Wv, bv, xt, Qt, Kt, Vb);
    k_attn<<<1024, 256, 0, stream>>>(Qt, Kt, Vb, x, gamma, out);
}

// Round 11
// 170.684 us; speedup vs baseline: 2.0209x; 1.2756x over previous
//
#include <hip/hip_runtime.h>
#include <hip/hip_bf16.h>

#define C_DIM 256
#define C8 32
#define N_DIM 4096
#define B_DIM 8
#define NSTEP (N_DIM / 32)   // 128 key-steps of 32

using bf16x8 = __attribute__((ext_vector_type(8))) __bf16;
using f32x4  = __attribute__((ext_vector_type(4))) float;
using f32x16 = __attribute__((ext_vector_type(16))) float;
using uint2v = __attribute__((ext_vector_type(2))) unsigned;

#define LOG2E 1.44269504088896f

// Tiled layouts (fragment-major, per batch):
//   Q/K: idx(n,d) = (n>>5)*1024 + (d>>3)*256 + (n&31)*8 + (d&7)    [N*32 elems]
//   V  : idx(c,n) = (n>>4)*4096 + ((n>>3)&1)*2048 + c*8 + (n&7)    [N*C elems]

// ---------------------------------------------------------------------------
// Kernel 0: x[b,c,n] f32  ->  xt[b,n,c] bf16   (LDS tile transpose)
// ---------------------------------------------------------------------------
__global__ __launch_bounds__(256) void k_transpose(
    const float* __restrict__ x, __bf16* __restrict__ xt)
{
    __shared__ float tile[64][65];
    int bid = blockIdx.x;
    int b  = bid >> 8;
    int ct = (bid >> 6) & 3;
    int nt = bid & 63;
    int c0 = ct * 64, n0 = nt * 64;
    int t = threadIdx.x;

    const float* xb = x + (size_t)b * C_DIM * N_DIM;
#pragma unroll
    for (int k = 0; k < 16; k++) {
        int idx = k * 256 + t;
        int i = idx >> 6, j = idx & 63;
        tile[i][j] = xb[(size_t)(c0 + i) * N_DIM + n0 + j];
    }
    __syncthreads();
    __bf16* xtb = xt + (size_t)b * N_DIM * C_DIM;
#pragma unroll
    for (int k = 0; k < 16; k++) {
        int idx = k * 256 + t;
        int nl = idx >> 6, cl = idx & 63;
        xtb[(size_t)(n0 + nl) * C_DIM + c0 + cl] = (__bf16)tile[cl][nl];
    }
}

// ---------------------------------------------------------------------------
// Kernel 1: QKV projection -> TILED outputs. Q pre-scaled by log2(e).
// ---------------------------------------------------------------------------
__global__ __launch_bounds__(256) void k_qkv(
    const float* __restrict__ Wq, const float* __restrict__ bq,
    const float* __restrict__ Wk, const float* __restrict__ bk,
    const float* __restrict__ Wv, const float* __restrict__ bv,
    const __bf16* __restrict__ xt,
    __bf16* __restrict__ Qt, __bf16* __restrict__ Kt, __bf16* __restrict__ Vb)
{
    int bid = blockIdx.x;
    int b   = bid / 320;
    int rem = bid % 320;
    int dt  = rem / 64;
    int nt  = rem % 64;
    int n0  = nt * 64;
    int wid  = threadIdx.x >> 6;
    int lane = threadIdx.x & 63;
    int lg = lane >> 4, li = lane & 15;
    int d0w = dt * 64 + wid * 16;

    int drow = d0w + li;
    const float* wrow;
    if (drow < 32)        wrow = Wq + drow * C_DIM;
    else if (drow < 64)   wrow = Wk + (drow - 32) * C_DIM;
    else                  wrow = Wv + (drow - 64) * C_DIM;

    const __bf16* xtb = xt + (size_t)b * N_DIM * C_DIM;

    f32x4 acc[4] = {};
#pragma unroll
    for (int ks = 0; ks < 8; ks++) {
        int c0 = ks * 32 + lg * 8;
        float4 w0 = *(const float4*)(wrow + c0);
        float4 w1 = *(const float4*)(wrow + c0 + 4);
        bf16x8 af;
        af[0] = (__bf16)w0.x; af[1] = (__bf16)w0.y;
        af[2] = (__bf16)w0.z; af[3] = (__bf16)w0.w;
        af[4] = (__bf16)w1.x; af[5] = (__bf16)w1.y;
        af[6] = (__bf16)w1.z; af[7] = (__bf16)w1.w;
#pragma unroll
        for (int ns = 0; ns < 4; ns++) {
            bf16x8 bfr = *(const bf16x8*)(xtb + (size_t)(n0 + ns * 16 + li) * C_DIM + ks * 32 + lg * 8);
            acc[ns] = __builtin_amdgcn_mfma_f32_16x16x32_bf16(af, bfr, acc[ns], 0, 0, 0);
        }
    }
    __bf16* Qtb = Qt + (size_t)b * (N_DIM * 32);
    __bf16* Ktb = Kt + (size_t)b * (N_DIM * 32);
    __bf16* Vtb = Vb + (size_t)b * (N_DIM * C_DIM);
#pragma unroll
    for (int r = 0; r < 4; r++) {
        int d = d0w + lg * 4 + r;
        float bias = (d < 32) ? bq[d] : (d < 64) ? bk[d - 32] : bv[d - 64];
#pragma unroll
        for (int ns = 0; ns < 4; ns++) {
            int n = n0 + ns * 16 + li;
            float v = acc[ns][r] + bias;
            if (d < 32) {
                int dd = d;
                Qtb[((n >> 5) << 10) + ((dd >> 3) << 8) + ((n & 31) << 3) + (dd & 7)]
                    = (__bf16)(v * LOG2E);
            } else if (d < 64) {
                int dd = d - 32;
                Ktb[((n >> 5) << 10) + ((dd >> 3) << 8) + ((n & 31) << 3) + (dd & 7)]
                    = (__bf16)v;
            } else {
                int c = d - 64;
                Vtb[((n >> 4) << 12) + (((n >> 3) & 1) << 11) + (c << 3) + (n & 7)]
                    = (__bf16)v;
            }
        }
    }
}

// ---------------------------------------------------------------------------
// helpers (numerics verified R7-R10: absmax matched)
// ---------------------------------------------------------------------------
static __device__ __forceinline__ unsigned pack2(float a, float b) {
    union { __bf16 h[2]; unsigned u; } c;
    c.h[0] = (__bf16)a; c.h[1] = (__bf16)b; return c.u;
}
static __device__ __forceinline__ bf16x8 mkfrag(unsigned d0, unsigned d1, unsigned d2, unsigned d3) {
    union { unsigned u[4]; bf16x8 v; } r;
    r.u[0] = d0; r.u[1] = d1; r.u[2] = d2; r.u[3] = d3; return r.v;
}
static __device__ __forceinline__ uint2v plswap(unsigned a, unsigned b) {
#if __has_builtin(__builtin_amdgcn_permlane32_swap)
    return __builtin_amdgcn_permlane32_swap(a, b, false, false);
#else
    unsigned ax = (unsigned)__shfl_xor((int)a, 32);
    unsigned bx = (unsigned)__shfl_xor((int)b, 32);
    int hi = (threadIdx.x >> 5) & 1;
    uint2v r;
    r.x = hi ? bx : a;
    r.y = hi ? b  : ax;
    return r;
#endif
}
// S~ (K·Q^T) 32x32 C/D block -> exp2 (NO shift: constant cancels in O/l)
// -> two PV B-fragments (16-key slices) + l partials.
static __device__ __forceinline__ void soft_pack(
    const f32x16& s, float& l, bf16x8& f0, bf16x8& f1)
{
    float p[16];
#pragma unroll
    for (int r = 0; r < 16; r++) p[r] = __builtin_amdgcn_exp2f(s[r]);
    float lp = 0.f;
#pragma unroll
    for (int r = 0; r < 16; r++) lp += p[r];
    l += lp;
    unsigned a0 = pack2(p[0],  p[1]),  b0 = pack2(p[2],  p[3]);
    unsigned a1 = pack2(p[4],  p[5]),  b1 = pack2(p[6],  p[7]);
    unsigned a2 = pack2(p[8],  p[9]),  b2 = pack2(p[10], p[11]);
    unsigned a3 = pack2(p[12], p[13]), b3 = pack2(p[14], p[15]);
    uint2v rA0 = plswap(a0, a1), rB0 = plswap(b0, b1);
    uint2v rA1 = plswap(a2, a3), rB1 = plswap(b2, b3);
    f0 = mkfrag(rA0.x, rB0.x, rA0.y, rB0.y);   // keys 0..15
    f1 = mkfrag(rA1.x, rB1.x, rA1.y, rB1.y);   // keys 16..31
}

// ---------------------------------------------------------------------------
// Kernel 2: barrier-free flash attention, ZERO softmax redundancy.
// Wave = 32 queries x ALL 256 channels x 4096 keys. 1024 waves = 1 wave/SIMD
// (256 blocks, 1/CU) -> full 512-reg budget. Software pipeline, 1-iteration
// load-use distance for K and V; source order QK(i+1) -> PV(i) ->
// softpack(i+1) so PV MFMAs cover s-latency and softpack VALU drains under
// the matrix-pipe backlog. Fused epilogue (gamma*acc/l + x).
// ---------------------------------------------------------------------------
__global__ __launch_bounds__(256, 1) void k_attn(
    const __bf16* __restrict__ Qt, const __bf16* __restrict__ Kt,
    const __bf16* __restrict__ Vb, const float* __restrict__ x,
    const float* __restrict__ gamma, float* __restrict__ out)
{
    int bid = blockIdx.x;            // 256 blocks, 1 per CU
    int b   = bid & 7;               // batch -> XCD affinity (K/V fit 4MB L2)
    int qg  = bid >> 3;              // 0..31 : group of 4 query-tiles
    int wid = threadIdx.x >> 6;
    int li  = threadIdx.x & 31;
    int hi  = (threadIdx.x >> 5) & 1;
    int n0q = (qg * 4 + wid) * 32;

    const __bf16* Qtb = Qt + (size_t)b * (N_DIM * 32);
    const __bf16* Ktb = Kt + (size_t)b * (N_DIM * 32);
    const __bf16* Vtb = Vb + (size_t)b * (N_DIM * C_DIM);

    const __bf16* Qlp = Qtb + ((n0q >> 5) << 10) + (hi << 8) + (li << 3);
    bf16x8 qf0 = *(const bf16x8*)(Qlp);        // d 0-15
    bf16x8 qf1 = *(const bf16x8*)(Qlp + 512);  // d 16-31

    const __bf16* Klp = Ktb + (hi << 8) + (li << 3);
    const __bf16* Vlp = Vtb + (hi << 11) + (li << 3);

    f32x16 acc0 = {}, acc1 = {}, acc2 = {}, acc3 = {};
    f32x16 acc4 = {}, acc5 = {}, acc6 = {}, acc7 = {};
    float l0 = 0.f;

    bf16x8 kA0, kA1, kB0, kB1;
    bf16x8 vA[16], vB[16];
    bf16x8 pA0, pA1, pB0, pB1;

#define KLOAD(D0, D1, S)                                                       \
    { const __bf16* Kn = Klp + ((size_t)(S) << 10);                            \
      D0 = *(const bf16x8*)(Kn); D1 = *(const bf16x8*)(Kn + 512); }

    // frag order: [ct*2 + ks]; addr = step<<13 + ks*4096 + ct*256
#define VLOAD(DST, S)                                                          \
    { const __bf16* Vn = Vlp + ((size_t)(S) << 13);                            \
      _Pragma("unroll")                                                        \
      for (int ct = 0; ct < 8; ct++) {                                         \
          DST[ct * 2 + 0] = *(const bf16x8*)(Vn + ct * 256);                   \
          DST[ct * 2 + 1] = *(const bf16x8*)(Vn + 4096 + ct * 256);            \
      } }

#define PVALL(V, P0, P1)                                                       \
    acc0 = __builtin_amdgcn_mfma_f32_32x32x16_bf16(V[0],  P0, acc0, 0, 0, 0);  \
    acc0 = __builtin_amdgcn_mfma_f32_32x32x16_bf16(V[1],  P1, acc0, 0, 0, 0);  \
    acc1 = __builtin_amdgcn_mfma_f32_32x32x16_bf16(V[2],  P0, acc1, 0, 0, 0);  \
    acc1 = __builtin_amdgcn_mfma_f32_32x32x16_bf16(V[3],  P1, acc1, 0, 0, 0);  \
    acc2 = __builtin_amdgcn_mfma_f32_32x32x16_bf16(V[4],  P0, acc2, 0, 0, 0);  \
    acc2 = __builtin_amdgcn_mfma_f32_32x32x16_bf16(V[5],  P1, acc2, 0, 0, 0);  \
    acc3 = __builtin_amdgcn_mfma_f32_32x32x16_bf16(V[6],  P0, acc3, 0, 0, 0);  \
    acc3 = __builtin_amdgcn_mfma_f32_32x32x16_bf16(V[7],  P1, acc3, 0, 0, 0);  \
    acc4 = __builtin_amdgcn_mfma_f32_32x32x16_bf16(V[8],  P0, acc4, 0, 0, 0);  \
    acc4 = __builtin_amdgcn_mfma_f32_32x32x16_bf16(V[9],  P1, acc4, 0, 0, 0);  \
    acc5 = __builtin_amdgcn_mfma_f32_32x32x16_bf16(V[10], P0, acc5, 0, 0, 0);  \
    acc5 = __builtin_amdgcn_mfma_f32_32x32x16_bf16(V[11], P1, acc5, 0, 0, 0);  \
    acc6 = __builtin_amdgcn_mfma_f32_32x32x16_bf16(V[12], P0, acc6, 0, 0, 0);  \
    acc6 = __builtin_amdgcn_mfma_f32_32x32x16_bf16(V[13], P1, acc6, 0, 0, 0);  \
    acc7 = __builtin_amdgcn_mfma_f32_32x32x16_bf16(V[14], P0, acc7, 0, 0, 0);  \
    acc7 = __builtin_amdgcn_mfma_f32_32x32x16_bf16(V[15], P1, acc7, 0, 0, 0);

    // BODY(I): load K(I+2)->KL, V(I+1)->VL; s=QK(I+1) from KU; PV(I) from
    // VU/PU (covers s latency); softpack(I+1)->PD (VALU under MFMA backlog).
#define BODY(I, KL0, KL1, VL, KU0, KU1, PD0, PD1, VU, PU0, PU1, KS)            \
    {                                                                          \
        KLOAD(KL0, KL1, KS)                                                    \
        VLOAD(VL, (I) + 1)                                                     \
        f32x16 z = {};                                                         \
        f32x16 s = __builtin_amdgcn_mfma_f32_32x32x16_bf16(KU0, qf0, z, 0, 0, 0); \
        s = __builtin_amdgcn_mfma_f32_32x32x16_bf16(KU1, qf1, s, 0, 0, 0);     \
        PVALL(VU, PU0, PU1)                                                    \
        soft_pack(s, l0, PD0, PD1);                                            \
    }

    // prologue: K(0),K(1),V(0); s(0); softpack(0)->pA
    KLOAD(kA0, kA1, 0)
    KLOAD(kB0, kB1, 1)
    VLOAD(vA, 0)
    {
        f32x16 z = {};
        f32x16 s = __builtin_amdgcn_mfma_f32_32x32x16_bf16(kA0, qf0, z, 0, 0, 0);
        s = __builtin_amdgcn_mfma_f32_32x32x16_bf16(kA1, qf1, s, 0, 0, 0);
        soft_pack(s, l0, pA0, pA1);
    }

    for (int i = 0; i < 126; i += 2) {
        BODY(i,     kA0, kA1, vB, kB0, kB1, pB0, pB1, vA, pA0, pA1, i + 2)
        BODY(i + 1, kB0, kB1, vA, kA0, kA1, pA0, pA1, vB, pB0, pB1, i + 3)
    }
    // i = 126: K reload of 127 (harmless), V(127), QK(127), PV(126)
    BODY(126, kA0, kA1, vB, kB0, kB1, pB0, pB1, vA, pA0, pA1, 127)
    // tail: PV(127)
    PVALL(vB, pB0, pB1)

#undef BODY
#undef PVALL
#undef VLOAD
#undef KLOAD

    // ---- epilogue: l reduce across hi halves, fused gamma/l + residual
    float lv = l0 + __shfl_xor(l0, 32);
    float linv = gamma[0] / lv;

#define STORE_ACC(A, G)                                                        \
    _Pragma("unroll")                                                          \
    for (int rg = 0; rg < 16; rg++) {                                          \
        int row = (rg & 3) + 8 * (rg >> 2) + 4 * hi;                           \
        size_t idx = ((size_t)b * C_DIM + ((G) * 32 + row)) * N_DIM            \
                     + (n0q + li);                                             \
        out[idx] = A[rg] * linv + x[idx];                                      \
    }
    STORE_ACC(acc0, 0)
    STORE_ACC(acc1, 1)
    STORE_ACC(acc2, 2)
    STORE_ACC(acc3, 3)
    STORE_ACC(acc4, 4)
    STORE_ACC(acc5, 5)
    STORE_ACC(acc6, 6)
    STORE_ACC(acc7, 7)
#undef STORE_ACC
}

// ---------------------------------------------------------------------------
extern "C" void kernel_launch(void* const* d_in, const int* in_sizes, int n_in,
                              void* d_out, int out_size, void* d_ws, size_t ws_size,
                              hipStream_t stream)
{
    const float* x     = (const float*)d_in[0];
    const float* Wq    = (const float*)d_in[1];
    const float* bq    = (const float*)d_in[2];
    const float* Wk    = (const float*)d_in[3];
    const float* bk    = (const float*)d_in[4];
    const float* Wv    = (const float*)d_in[5];
    const float* bv    = (const float*)d_in[6];
    const float* gamma = (const float*)d_in[7];
    float* out = (float*)d_out;

    char* ws = (char*)d_ws;
    const size_t MB = 1024 * 1024;
    __bf16* xt = (__bf16*)ws;                      // 16 MiB
    __bf16* Qt = (__bf16*)(ws + 16 * MB);          //  2 MiB (tiled)
    __bf16* Kt = (__bf16*)(ws + 18 * MB);          //  2 MiB (tiled)
    __bf16* Vb = (__bf16*)(ws + 20 * MB);          // 16 MiB (tiled)

    k_transpose<<<2048, 256, 0, stream>>>(x, xt);
    k_qkv<<<2560, 256, 0, stream>>>(Wq, bq, Wk, bk, Wv, bv, xt, Qt, Kt, Vb);
    k_attn<<<256, 256, 0, stream>>>(Qt, Kt, Vb, x, gamma, out);
}